// Round 6
// baseline (754.312 us; speedup 1.0000x reference)
//
#include <hip/hip_runtime.h>

#define N_NODES 50000
#define N_EDGES 800000
#define IN_F 512
#define H_F 128
#define OUT_F 64

// ---------------- graph prep ----------------
// Harness ABI says integer -> const int*, but reference declares int64.
// Auto-detect: read first 256 entries as int64; all in [0,N_NODES) => int64.

__global__ void detect_kernel(const void* __restrict__ edges, int* __restrict__ flag) {
    if (threadIdx.x == 0 && blockIdx.x == 0) {
        const long long* p = (const long long*)edges;
        int is64 = 1;
        for (int k = 0; k < 256; k++) {
            long long v = p[k];
            if (v < 0 || v >= N_NODES) { is64 = 0; break; }
        }
        flag[0] = is64;
    }
}

__device__ __forceinline__ int edge_at(const void* __restrict__ p, int e, int is64) {
    return is64 ? (int)((const long long*)p)[e] : ((const int*)p)[e];
}

__global__ void count_kernel(const void* __restrict__ src, const void* __restrict__ dst,
                             int* __restrict__ cs, int* __restrict__ cd,
                             const int* __restrict__ flag) {
    int is64 = flag[0];
    int e = blockIdx.x * 256 + threadIdx.x;
    if (e < N_EDGES) {
        atomicAdd(&cs[edge_at(src, e, is64)], 1);
        atomicAdd(&cd[edge_at(dst, e, is64)], 1);
    }
}

__global__ void scan_kernel(const int* __restrict__ in, int* __restrict__ exc,
                            int* __restrict__ bsums, int n) {
    __shared__ int tmp[1024];
    int tid = threadIdx.x;
    int gid = blockIdx.x * 1024 + tid;
    int v = (gid < n) ? in[gid] : 0;
    tmp[tid] = v;
    __syncthreads();
    for (int off = 1; off < 1024; off <<= 1) {
        int t = (tid >= off) ? tmp[tid - off] : 0;
        __syncthreads();
        tmp[tid] += t;
        __syncthreads();
    }
    if (gid < n) exc[gid] = tmp[tid] - v;   // exclusive
    if (tid == 1023) bsums[blockIdx.x] = tmp[1023];
}

__global__ void finalize_kernel(const int* __restrict__ exc, const int* __restrict__ bexc,
                                int* __restrict__ rp, int* __restrict__ cur,
                                const int* __restrict__ cs, const int* __restrict__ cd,
                                float* __restrict__ ns, float* __restrict__ nd) {
    int i = blockIdx.x * 256 + threadIdx.x;
    if (i < N_NODES) {
        int v = exc[i] + bexc[i >> 10];
        rp[i] = v;
        cur[i] = v;
        if (i == 0) rp[N_NODES] = N_EDGES;
        ns[i] = 1.0f / sqrtf(fmaxf((float)cs[i], 1.0f));
        nd[i] = 1.0f / sqrtf(fmaxf((float)cd[i], 1.0f));
    }
}

__global__ void fill_kernel(const void* __restrict__ src, const void* __restrict__ dst,
                            int* __restrict__ cur, int* __restrict__ col,
                            const int* __restrict__ flag) {
    int is64 = flag[0];
    int e = blockIdx.x * 256 + threadIdx.x;
    if (e < N_EDGES) {
        int d = edge_at(dst, e, is64);
        int pos = atomicAdd(&cur[d], 1);
        col[pos] = edge_at(src, e, is64);
    }
}

// ---------------- GEMM: C[M,N] = norm[row] * (A @ W), fp32 vector, 2-phase pipelined ----------
// Reg-staged prefetch: issue tile t+1 global loads BEFORE computing tile t from LDS;
// ds_write after the post-compute barrier (single LDS buffer suffices with reg staging).
// Ast transposed [32][BM+4] (a-frag reads broadcast, conflict-free);
// Ws skewed f->f+(f>>3) (w-frag reads 2-way = free, m136).

__device__ __forceinline__ constexpr int swz(int f) { return f + (f >> 3); }

template <int N, int BM, bool COPY>
__global__ __launch_bounds__(256) void gemm_norm(const float* __restrict__ A, const float* __restrict__ W,
                                                 const float* __restrict__ norm, float* __restrict__ C,
                                                 int K, float* __restrict__ xc) {
    constexpr int TX = N / 8;            // 16 (N=128) / 8 (N=64)
    constexpr int TY = 256 / TX;         // 16 / 32
    constexpr int RT = BM / TY;          // 4 (64,128) / 4 (128,64)
    constexpr int NF4 = N / 4;           // 32 / 16
    constexpr int SA = BM + 4;           // Ast stride (floats), mult of 4
    constexpr int SW = (swz(NF4 - 1) + 1) * 4;  // Ws stride (floats): 140 / 68
    constexpr int APT = BM * 32 / 4 / 256;      // A float4s per thread: 2 / 4
    constexpr int WPT = 32 * NF4 / 256;         // W float4s per thread: 4 / 2

    __shared__ float Ast[32 * SA];
    __shared__ float Ws[32 * SW];

    const int t = threadIdx.x;
    const int tx = t % TX, ty = t / TX;
    const int m0 = blockIdx.x * BM;
    const int KT = K / 32;

    float4 abuf[APT], wbuf[WPT];

    auto load_tile = [&](int k0) {
        #pragma unroll
        for (int p = 0; p < APT; p++) {
            int idx = t + p * 256;
            int r = idx >> 3;
            int c = (idx & 7) << 2;
            int row = m0 + r;
            abuf[p] = make_float4(0.f, 0.f, 0.f, 0.f);
            if (row < N_NODES) abuf[p] = *(const float4*)&A[(size_t)row * K + k0 + c];
        }
        #pragma unroll
        for (int p = 0; p < WPT; p++) {
            int idx = t + p * 256;
            int r = idx / NF4;
            int f = idx % NF4;
            wbuf[p] = *(const float4*)&W[(size_t)(k0 + r) * N + f * 4];
        }
    };
    auto store_tile = [&](int k0) {
        #pragma unroll
        for (int p = 0; p < APT; p++) {
            int idx = t + p * 256;
            int r = idx >> 3;
            int c = (idx & 7) << 2;
            Ast[(c + 0) * SA + r] = abuf[p].x;
            Ast[(c + 1) * SA + r] = abuf[p].y;
            Ast[(c + 2) * SA + r] = abuf[p].z;
            Ast[(c + 3) * SA + r] = abuf[p].w;
            if (COPY) {
                int row = m0 + r;
                if (row < N_NODES) *(float4*)&xc[(size_t)row * K + k0 + c] = abuf[p];
            }
        }
        #pragma unroll
        for (int p = 0; p < WPT; p++) {
            int idx = t + p * 256;
            int r = idx / NF4;
            int f = idx % NF4;
            *(float4*)&Ws[r * SW + swz(f) * 4] = wbuf[p];
        }
    };

    float acc[RT][8];
    #pragma unroll
    for (int i = 0; i < RT; i++)
        #pragma unroll
        for (int j = 0; j < 8; j++) acc[i][j] = 0.f;

    load_tile(0);
    store_tile(0);
    __syncthreads();

    for (int kt = 0; kt < KT; kt++) {
        if (kt + 1 < KT) load_tile((kt + 1) * 32);   // issue early; consumed after barrier
        #pragma unroll 8
        for (int kk = 0; kk < 32; kk++) {
            float a[RT], w[8];
            #pragma unroll
            for (int r4 = 0; r4 < RT / 4; r4++)
                *(float4*)&a[r4 * 4] = *(const float4*)&Ast[kk * SA + ty * RT + r4 * 4];
            int f0 = tx * 2;
            *(float4*)&w[0] = *(const float4*)&Ws[kk * SW + (f0 + (f0 >> 3)) * 4];
            *(float4*)&w[4] = *(const float4*)&Ws[kk * SW + (f0 + 1 + ((f0 + 1) >> 3)) * 4];
            #pragma unroll
            for (int i = 0; i < RT; i++)
                #pragma unroll
                for (int j = 0; j < 8; j++) acc[i][j] = fmaf(a[i], w[j], acc[i][j]);
        }
        __syncthreads();
        if (kt + 1 < KT) {
            store_tile((kt + 1) * 32);               // waits vmcnt here, not before compute
            __syncthreads();
        }
    }

    #pragma unroll
    for (int i = 0; i < RT; i++) {
        int row = m0 + ty * RT + i;
        if (row < N_NODES) {
            float s = norm[row];
            float4 o0 = make_float4(acc[i][0] * s, acc[i][1] * s, acc[i][2] * s, acc[i][3] * s);
            float4 o1 = make_float4(acc[i][4] * s, acc[i][5] * s, acc[i][6] * s, acc[i][7] * s);
            *(float4*)&C[(size_t)row * N + tx * 8] = o0;
            *(float4*)&C[(size_t)row * N + tx * 8 + 4] = o1;
        }
    }
}

// ---------------- SpMM: out[i,:] = relu?(nd[i]*sum_{e in row i} h[col[e],:] + b) ----------
// One wave per node; lane holds float2 (FEAT=128) or float (FEAT=64).
// 8-edge unroll -> 8 gather loads in flight per wave (MLP). rp/col scalar via uniform i.

template <int FEAT, bool RELU, bool HID>
__global__ __launch_bounds__(256) void spmm_kernel(
        const float* __restrict__ h, const int* __restrict__ rp,
        const int* __restrict__ col, const float* __restrict__ nd,
        const float* __restrict__ bias, float* __restrict__ out,
        float* __restrict__ hid, const int* __restrict__ emb, int layer) {
    int i = blockIdx.x * 4 + (threadIdx.x >> 6);
    i = __builtin_amdgcn_readfirstlane(i);
    if (i >= N_NODES) return;
    int lane = threadIdx.x & 63;
    int beg = rp[i], end = rp[i + 1];

    if constexpr (FEAT == 128) {
        float ax = 0.f, ay = 0.f;
        int e = beg;
        for (; e + 8 <= end; e += 8) {
            int c0 = col[e], c1 = col[e+1], c2 = col[e+2], c3 = col[e+3];
            int c4 = col[e+4], c5 = col[e+5], c6 = col[e+6], c7 = col[e+7];
            float2 v0 = *(const float2*)&h[(size_t)c0 * FEAT + lane * 2];
            float2 v1 = *(const float2*)&h[(size_t)c1 * FEAT + lane * 2];
            float2 v2 = *(const float2*)&h[(size_t)c2 * FEAT + lane * 2];
            float2 v3 = *(const float2*)&h[(size_t)c3 * FEAT + lane * 2];
            float2 v4 = *(const float2*)&h[(size_t)c4 * FEAT + lane * 2];
            float2 v5 = *(const float2*)&h[(size_t)c5 * FEAT + lane * 2];
            float2 v6 = *(const float2*)&h[(size_t)c6 * FEAT + lane * 2];
            float2 v7 = *(const float2*)&h[(size_t)c7 * FEAT + lane * 2];
            ax += (v0.x + v1.x) + (v2.x + v3.x) + ((v4.x + v5.x) + (v6.x + v7.x));
            ay += (v0.y + v1.y) + (v2.y + v3.y) + ((v4.y + v5.y) + (v6.y + v7.y));
        }
        for (; e < end; e++) {
            float2 v = *(const float2*)&h[(size_t)col[e] * FEAT + lane * 2];
            ax += v.x; ay += v.y;
        }
        float s = nd[i];
        float2 b = *(const float2*)&bias[lane * 2];
        float vx = fmaf(ax, s, b.x), vy = fmaf(ay, s, b.y);
        if (RELU) { vx = fmaxf(vx, 0.f); vy = fmaxf(vy, 0.f); }
        float2 o = make_float2(vx, vy);
        *(float2*)&out[(size_t)i * FEAT + lane * 2] = o;
        if (HID) {
            if (emb[0] == layer) *(float2*)&hid[(size_t)i * FEAT + lane * 2] = o;
        }
    } else {
        float acc = 0.f;
        int e = beg;
        for (; e + 8 <= end; e += 8) {
            int c0 = col[e], c1 = col[e+1], c2 = col[e+2], c3 = col[e+3];
            int c4 = col[e+4], c5 = col[e+5], c6 = col[e+6], c7 = col[e+7];
            float v0 = h[(size_t)c0 * FEAT + lane];
            float v1 = h[(size_t)c1 * FEAT + lane];
            float v2 = h[(size_t)c2 * FEAT + lane];
            float v3 = h[(size_t)c3 * FEAT + lane];
            float v4 = h[(size_t)c4 * FEAT + lane];
            float v5 = h[(size_t)c5 * FEAT + lane];
            float v6 = h[(size_t)c6 * FEAT + lane];
            float v7 = h[(size_t)c7 * FEAT + lane];
            acc += (v0 + v1) + (v2 + v3) + ((v4 + v5) + (v6 + v7));
        }
        for (; e < end; e++) acc += h[(size_t)col[e] * FEAT + lane];
        float v = fmaf(acc, nd[i], bias[lane]);
        if (RELU) v = fmaxf(v, 0.f);
        out[(size_t)i * FEAT + lane] = v;
        if (HID) {
            if (emb[0] == layer) hid[(size_t)i * FEAT + lane] = v;
        }
    }
}

// ---------------- launch ----------------

extern "C" void kernel_launch(void* const* d_in, const int* in_sizes, int n_in,
                              void* d_out, int out_size, void* d_ws, size_t ws_size,
                              hipStream_t stream) {
    const float* x = (const float*)d_in[0];
    const void* src = d_in[1];
    const void* dst = d_in[2];
    const float* W1 = (const float*)d_in[3];  const float* b1 = (const float*)d_in[4];
    const float* W2 = (const float*)d_in[5];  const float* b2 = (const float*)d_in[6];
    const float* W3 = (const float*)d_in[7];  const float* b3 = (const float*)d_in[8];
    const float* W4 = (const float*)d_in[9];  const float* b4 = (const float*)d_in[10];
    const int* emb = (const int*)d_in[11];    // low word correct for int32 or int64
    float* out = (float*)d_out;

    // workspace carve-up (~53 MB)
    char* w = (char*)d_ws;
    int* cnt_src = (int*)w;  w += 51200 * 4;
    int* cnt_dst = (int*)w;  w += 51200 * 4;
    float* norm_src = (float*)w; w += 51200 * 4;
    float* norm_dst = (float*)w; w += 51200 * 4;
    int* exc = (int*)w;      w += 51200 * 4;
    int* bsums = (int*)w;    w += 1024 * 4;
    int* bexc = (int*)w;     w += 1024 * 4;
    int* bdummy = (int*)w;   w += 1024 * 4;
    int* dflag = (int*)w;    w += 1024 * 4;
    int* rp = (int*)w;       w += 51200 * 4;
    int* cur = (int*)w;      w += 51200 * 4;
    int* col = (int*)w;      w += 800768 * 4;
    float* gbuf = (float*)w; w += (size_t)6400000 * 4;   // GEMM output (pre-aggregation)
    float* hbuf = (float*)w; w += (size_t)6400000 * 4;   // SpMM output

    // graph prep
    hipMemsetAsync(cnt_src, 0, 2 * 51200 * 4, stream);
    detect_kernel<<<1, 64, 0, stream>>>(dst, dflag);
    count_kernel<<<3125, 256, 0, stream>>>(src, dst, cnt_src, cnt_dst, dflag);
    scan_kernel<<<49, 1024, 0, stream>>>(cnt_dst, exc, bsums, N_NODES);
    scan_kernel<<<1, 1024, 0, stream>>>(bsums, bexc, bdummy, 49);
    finalize_kernel<<<196, 256, 0, stream>>>(exc, bexc, rp, cur,
                                             cnt_src, cnt_dst, norm_src, norm_dst);
    fill_kernel<<<3125, 256, 0, stream>>>(src, dst, cur, col, dflag);

    const int GB64 = (N_NODES + 63) / 64;     // 782 blocks (BM=64, N=128 layers)
    const int GB128 = (N_NODES + 127) / 128;  // 391 blocks (BM=128, N=64 layer)
    const int SB = (N_NODES + 3) / 4;         // 12500 blocks (4 waves = 4 nodes)
    float* hid = out + (size_t)N_NODES * OUT_F;
    float* xcopy = hid + (size_t)N_NODES * H_F;

    // layer 1: 512 -> 128, relu  (fuses x passthrough copy into staging write-phase)
    gemm_norm<128, 64, true><<<GB64, 256, 0, stream>>>(x, W1, norm_src, gbuf, IN_F, xcopy);
    spmm_kernel<128, true, true><<<SB, 256, 0, stream>>>(gbuf, rp, col, norm_dst, b1, hbuf, hid, emb, 1);

    // layer 2: 128 -> 128, relu
    gemm_norm<128, 64, false><<<GB64, 256, 0, stream>>>(hbuf, W2, norm_src, gbuf, H_F, nullptr);
    spmm_kernel<128, true, true><<<SB, 256, 0, stream>>>(gbuf, rp, col, norm_dst, b2, hbuf, hid, emb, 2);

    // layer 3: 128 -> 128, relu
    gemm_norm<128, 64, false><<<GB64, 256, 0, stream>>>(hbuf, W3, norm_src, gbuf, H_F, nullptr);
    spmm_kernel<128, true, true><<<SB, 256, 0, stream>>>(gbuf, rp, col, norm_dst, b3, hbuf, hid, emb, 3);

    // layer 4: 128 -> 64, no relu, straight into d_out
    gemm_norm<64, 128, false><<<GB128, 256, 0, stream>>>(hbuf, W4, norm_src, gbuf, H_F, nullptr);
    spmm_kernel<64, false, false><<<SB, 256, 0, stream>>>(gbuf, rp, col, norm_dst, b4, out, nullptr, nullptr, 0);
}

// Round 8
// 648.568 us; speedup vs baseline: 1.1630x; 1.1630x over previous
//
#include <hip/hip_runtime.h>

#define N_NODES 50000
#define N_EDGES 800000
#define IN_F 512
#define H_F 128
#define OUT_F 64

// ---------------- graph prep ----------------
// Harness ABI says integer -> const int*, but reference declares int64.
// Auto-detect: read first 256 entries as int64; all in [0,N_NODES) => int64.

__global__ void detect_kernel(const void* __restrict__ edges, int* __restrict__ flag) {
    if (threadIdx.x == 0 && blockIdx.x == 0) {
        const long long* p = (const long long*)edges;
        int is64 = 1;
        for (int k = 0; k < 256; k++) {
            long long v = p[k];
            if (v < 0 || v >= N_NODES) { is64 = 0; break; }
        }
        flag[0] = is64;
    }
}

__device__ __forceinline__ int edge_at(const void* __restrict__ p, int e, int is64) {
    return is64 ? (int)((const long long*)p)[e] : ((const int*)p)[e];
}

__global__ void count_kernel(const void* __restrict__ src, const void* __restrict__ dst,
                             int* __restrict__ cs, int* __restrict__ cd,
                             const int* __restrict__ flag) {
    int is64 = flag[0];
    int e = blockIdx.x * 256 + threadIdx.x;
    if (e < N_EDGES) {
        atomicAdd(&cs[edge_at(src, e, is64)], 1);
        atomicAdd(&cd[edge_at(dst, e, is64)], 1);
    }
}

__global__ void scan_kernel(const int* __restrict__ in, int* __restrict__ exc,
                            int* __restrict__ bsums, int n) {
    __shared__ int tmp[1024];
    int tid = threadIdx.x;
    int gid = blockIdx.x * 1024 + tid;
    int v = (gid < n) ? in[gid] : 0;
    tmp[tid] = v;
    __syncthreads();
    for (int off = 1; off < 1024; off <<= 1) {
        int t = (tid >= off) ? tmp[tid - off] : 0;
        __syncthreads();
        tmp[tid] += t;
        __syncthreads();
    }
    if (gid < n) exc[gid] = tmp[tid] - v;   // exclusive
    if (tid == 1023) bsums[blockIdx.x] = tmp[1023];
}

__global__ void finalize_kernel(const int* __restrict__ exc, const int* __restrict__ bexc,
                                int* __restrict__ rp, int* __restrict__ cur,
                                const int* __restrict__ cs, const int* __restrict__ cd,
                                float* __restrict__ ns, float* __restrict__ nd) {
    int i = blockIdx.x * 256 + threadIdx.x;
    if (i < N_NODES) {
        int v = exc[i] + bexc[i >> 10];
        rp[i] = v;
        cur[i] = v;
        if (i == 0) rp[N_NODES] = N_EDGES;
        ns[i] = 1.0f / sqrtf(fmaxf((float)cs[i], 1.0f));
        nd[i] = 1.0f / sqrtf(fmaxf((float)cd[i], 1.0f));
    }
}

__global__ void fill_kernel(const void* __restrict__ src, const void* __restrict__ dst,
                            int* __restrict__ cur, int* __restrict__ col,
                            const int* __restrict__ flag) {
    int is64 = flag[0];
    int e = blockIdx.x * 256 + threadIdx.x;
    if (e < N_EDGES) {
        int d = edge_at(dst, e, is64);
        int pos = atomicAdd(&cur[d], 1);
        col[pos] = edge_at(src, e, is64);
    }
}

// ---------------- bf16 split helpers (RNE) ----------------

__device__ __forceinline__ ushort f2bf(float f) {
    unsigned int u = __float_as_uint(f);
    unsigned int r = u + 0x7FFFu + ((u >> 16) & 1u);
    return (ushort)(r >> 16);
}
__device__ __forceinline__ float bf2f(ushort h) {
    return __uint_as_float(((unsigned int)h) << 16);
}

// ---------------- W pre-convert: fp32 [K][N] -> fragment-linear bf16 hi/lo ----------------
// Frag element index for (k,n): kt=k>>5, kk=k&31, ns=n>>4;
// lane=(n&15)+16*(kk>>3), j=kk&7; dst = base + ((kt*NS+ns)*64+lane)*8 + j.
// k-map kappa(g,j)=8g+j is used identically for A and B staging, so the GEMM
// result is invariant to the hardware's internal k-ordering (consistent perm).

__global__ void wconv_kernel(const float* __restrict__ W1, const float* __restrict__ W2,
                             const float* __restrict__ W3, const float* __restrict__ W4,
                             ushort* __restrict__ hi, ushort* __restrict__ lo) {
    int id = blockIdx.x * 256 + threadIdx.x;
    const float* Wp; int N, rel, base;
    if (id < 65536)       { Wp = W1; N = 128; rel = id;          base = 0; }
    else if (id < 81920)  { Wp = W2; N = 128; rel = id - 65536;  base = 65536; }
    else if (id < 98304)  { Wp = W3; N = 128; rel = id - 81920;  base = 81920; }
    else if (id < 106496) { Wp = W4; N = 64;  rel = id - 98304;  base = 98304; }
    else return;
    int k = rel / N, n = rel % N;
    float v = Wp[rel];
    int NS = N >> 4;
    int kt = k >> 5, kk = k & 31, ns = n >> 4;
    int lane = (n & 15) + 16 * (kk >> 3), j = kk & 7;
    int dst = base + ((kt * NS + ns) * 64 + lane) * 8 + j;
    ushort h = f2bf(v);
    hi[dst] = h;
    lo[dst] = f2bf(v - bf2f(h));
}

// ---------------- GEMM via MFMA: C[M,N] = norm[row] * (A @ W), split-bf16 ----------------
// BM=32 rows/block (2 row-subtiles), 256 thr = 4 waves; wave w owns rowsub=w&1,
// n-subtiles nsb..nsb+NSW-1 (nsb=(w>>1)*NSW). Per k-step (BK=32): 3 MFMAs/tile
// (hihi + hi*lo + lo*hi; lo*lo ~2^-16 dropped). A split in-kernel via 4 KB LDS
// (fragment-linear: lane reads 16B at lane*16 -> conflict-free). B frags read
// directly from preconverted global (L2-resident, lane-contiguous dwordx4).
// C/D layout (HW-verified m89/m91): col=lane&15, row=(lane>>4)*4+reg.

typedef __attribute__((ext_vector_type(8))) short short8v;   // 8 bf16 (4 VGPRs)
typedef __attribute__((ext_vector_type(4))) float floatx4;

template <int N, bool COPY>
__global__ __launch_bounds__(256) void gemm_mfma(const float* __restrict__ A,
                                                 const ushort* __restrict__ Whi,
                                                 const ushort* __restrict__ Wlo,
                                                 const float* __restrict__ norm,
                                                 float* __restrict__ C, int K,
                                                 float* __restrict__ xc) {
    constexpr int NS = N / 16;       // 8 (N=128) / 4 (N=64)
    constexpr int NSW = NS / 2;      // tiles per wave: 4 / 2

    __shared__ ushort Ahi[2][64][8];
    __shared__ ushort Alo[2][64][8];

    const int t = threadIdx.x;
    const int w = t >> 6, lane = t & 63;
    const int rowsub = w & 1, nsb = (w >> 1) * NSW;
    const int m0 = blockIdx.x * 32;
    // staging coords: thread t loads A[row= m0+(t>>3)][k0 + (t&7)*4 .. +3]
    const int sr = t >> 3;                    // 0..31
    const int sc = (t & 7) << 2;              // 0,4,..,28
    const int ss = sr >> 4;                   // subtile
    const int sl = (sr & 15) + 16 * (sc >> 3);// dest lane
    const int sj = sc & 7;                    // dest j (0 or 4)
    const int row = m0 + sr;
    const int KT = K >> 5;

    floatx4 acc[NSW];
    #pragma unroll
    for (int q = 0; q < NSW; q++) acc[q] = (floatx4)(0.0f);

    for (int kt = 0; kt < KT; kt++) {
        // B fragments: direct global (L2-resident), issued first for latency
        short8v bhi[NSW], blo[NSW];
        #pragma unroll
        for (int q = 0; q < NSW; q++) {
            size_t fb = ((size_t)(kt * NS + nsb + q) * 64 + lane) * 8;
            bhi[q] = *(const short8v*)&Whi[fb];
            blo[q] = *(const short8v*)&Wlo[fb];
        }
        // stage A: load fp32, split hi/lo, write fragment-linear LDS
        float4 v = make_float4(0.f, 0.f, 0.f, 0.f);
        if (row < N_NODES) {
            v = *(const float4*)&A[(size_t)row * K + kt * 32 + sc];
            if (COPY) *(float4*)&xc[(size_t)row * K + kt * 32 + sc] = v;
        }
        ushort4 h4, l4;
        h4.x = f2bf(v.x); l4.x = f2bf(v.x - bf2f(h4.x));
        h4.y = f2bf(v.y); l4.y = f2bf(v.y - bf2f(h4.y));
        h4.z = f2bf(v.z); l4.z = f2bf(v.z - bf2f(h4.z));
        h4.w = f2bf(v.w); l4.w = f2bf(v.w - bf2f(h4.w));
        *(ushort4*)&Ahi[ss][sl][sj] = h4;
        *(ushort4*)&Alo[ss][sl][sj] = l4;
        __syncthreads();

        short8v ah = *(const short8v*)&Ahi[rowsub][lane][0];
        short8v al = *(const short8v*)&Alo[rowsub][lane][0];
        #pragma unroll
        for (int q = 0; q < NSW; q++) {
            acc[q] = __builtin_amdgcn_mfma_f32_16x16x32_bf16(ah, bhi[q], acc[q], 0, 0, 0);
            acc[q] = __builtin_amdgcn_mfma_f32_16x16x32_bf16(ah, blo[q], acc[q], 0, 0, 0);
            acc[q] = __builtin_amdgcn_mfma_f32_16x16x32_bf16(al, bhi[q], acc[q], 0, 0, 0);
        }
        __syncthreads();
    }

    // epilogue: C[gr][gc] = acc * norm[gr]
    #pragma unroll
    for (int rr = 0; rr < 4; rr++) {
        int gr = m0 + rowsub * 16 + (lane >> 4) * 4 + rr;
        if (gr < N_NODES) {
            float s = norm[gr];
            #pragma unroll
            for (int q = 0; q < NSW; q++) {
                int gc = (nsb + q) * 16 + (lane & 15);
                C[(size_t)gr * N + gc] = acc[q][rr] * s;
            }
        }
    }
}

// ---------------- SpMM: out[i,:] = relu?(nd[i]*sum_{e in row i} h[col[e],:] + b) ----------
// One wave per node; lane holds float2 (FEAT=128) or float (FEAT=64).
// 8-edge unroll -> 8 gather loads in flight per wave. rp/col scalar via uniform i.

template <int FEAT, bool RELU, bool HID>
__global__ __launch_bounds__(256) void spmm_kernel(
        const float* __restrict__ h, const int* __restrict__ rp,
        const int* __restrict__ col, const float* __restrict__ nd,
        const float* __restrict__ bias, float* __restrict__ out,
        float* __restrict__ hid, const int* __restrict__ emb, int layer) {
    int i = blockIdx.x * 4 + (threadIdx.x >> 6);
    i = __builtin_amdgcn_readfirstlane(i);
    if (i >= N_NODES) return;
    int lane = threadIdx.x & 63;
    int beg = rp[i], end = rp[i + 1];

    if constexpr (FEAT == 128) {
        float ax = 0.f, ay = 0.f;
        int e = beg;
        for (; e + 8 <= end; e += 8) {
            int c0 = col[e], c1 = col[e+1], c2 = col[e+2], c3 = col[e+3];
            int c4 = col[e+4], c5 = col[e+5], c6 = col[e+6], c7 = col[e+7];
            float2 v0 = *(const float2*)&h[(size_t)c0 * FEAT + lane * 2];
            float2 v1 = *(const float2*)&h[(size_t)c1 * FEAT + lane * 2];
            float2 v2 = *(const float2*)&h[(size_t)c2 * FEAT + lane * 2];
            float2 v3 = *(const float2*)&h[(size_t)c3 * FEAT + lane * 2];
            float2 v4 = *(const float2*)&h[(size_t)c4 * FEAT + lane * 2];
            float2 v5 = *(const float2*)&h[(size_t)c5 * FEAT + lane * 2];
            float2 v6 = *(const float2*)&h[(size_t)c6 * FEAT + lane * 2];
            float2 v7 = *(const float2*)&h[(size_t)c7 * FEAT + lane * 2];
            ax += (v0.x + v1.x) + (v2.x + v3.x) + ((v4.x + v5.x) + (v6.x + v7.x));
            ay += (v0.y + v1.y) + (v2.y + v3.y) + ((v4.y + v5.y) + (v6.y + v7.y));
        }
        for (; e < end; e++) {
            float2 v = *(const float2*)&h[(size_t)col[e] * FEAT + lane * 2];
            ax += v.x; ay += v.y;
        }
        float s = nd[i];
        float2 b = *(const float2*)&bias[lane * 2];
        float vx = fmaf(ax, s, b.x), vy = fmaf(ay, s, b.y);
        if (RELU) { vx = fmaxf(vx, 0.f); vy = fmaxf(vy, 0.f); }
        float2 o = make_float2(vx, vy);
        *(float2*)&out[(size_t)i * FEAT + lane * 2] = o;
        if (HID) {
            if (emb[0] == layer) *(float2*)&hid[(size_t)i * FEAT + lane * 2] = o;
        }
    } else {
        float acc = 0.f;
        int e = beg;
        for (; e + 8 <= end; e += 8) {
            int c0 = col[e], c1 = col[e+1], c2 = col[e+2], c3 = col[e+3];
            int c4 = col[e+4], c5 = col[e+5], c6 = col[e+6], c7 = col[e+7];
            float v0 = h[(size_t)c0 * FEAT + lane];
            float v1 = h[(size_t)c1 * FEAT + lane];
            float v2 = h[(size_t)c2 * FEAT + lane];
            float v3 = h[(size_t)c3 * FEAT + lane];
            float v4 = h[(size_t)c4 * FEAT + lane];
            float v5 = h[(size_t)c5 * FEAT + lane];
            float v6 = h[(size_t)c6 * FEAT + lane];
            float v7 = h[(size_t)c7 * FEAT + lane];
            acc += (v0 + v1) + (v2 + v3) + ((v4 + v5) + (v6 + v7));
        }
        for (; e < end; e++) acc += h[(size_t)col[e] * FEAT + lane];
        float v = fmaf(acc, nd[i], bias[lane]);
        if (RELU) v = fmaxf(v, 0.f);
        out[(size_t)i * FEAT + lane] = v;
        if (HID) {
            if (emb[0] == layer) hid[(size_t)i * FEAT + lane] = v;
        }
    }
}

// ---------------- launch ----------------

extern "C" void kernel_launch(void* const* d_in, const int* in_sizes, int n_in,
                              void* d_out, int out_size, void* d_ws, size_t ws_size,
                              hipStream_t stream) {
    const float* x = (const float*)d_in[0];
    const void* src = d_in[1];
    const void* dst = d_in[2];
    const float* W1 = (const float*)d_in[3];  const float* b1 = (const float*)d_in[4];
    const float* W2 = (const float*)d_in[5];  const float* b2 = (const float*)d_in[6];
    const float* W3 = (const float*)d_in[7];  const float* b3 = (const float*)d_in[8];
    const float* W4 = (const float*)d_in[9];  const float* b4 = (const float*)d_in[10];
    const int* emb = (const int*)d_in[11];    // low word correct for int32 or int64
    float* out = (float*)d_out;

    // workspace carve-up (~54 MB)
    char* w = (char*)d_ws;
    int* cnt_src = (int*)w;  w += 51200 * 4;
    int* cnt_dst = (int*)w;  w += 51200 * 4;
    float* norm_src = (float*)w; w += 51200 * 4;
    float* norm_dst = (float*)w; w += 51200 * 4;
    int* exc = (int*)w;      w += 51200 * 4;
    int* bsums = (int*)w;    w += 1024 * 4;
    int* bexc = (int*)w;     w += 1024 * 4;
    int* bdummy = (int*)w;   w += 1024 * 4;
    int* dflag = (int*)w;    w += 1024 * 4;
    int* rp = (int*)w;       w += 51200 * 4;
    int* cur = (int*)w;      w += 51200 * 4;
    int* col = (int*)w;      w += 800768 * 4;
    float* gbuf = (float*)w; w += (size_t)6400000 * 4;   // GEMM output (pre-aggregation)
    float* hbuf = (float*)w; w += (size_t)6400000 * 4;   // SpMM output
    ushort* whi = (ushort*)w; w += 106496 * 2;           // W frags, bf16 hi
    ushort* wlo = (ushort*)w; w += 106496 * 2;           // W frags, bf16 lo

    // graph prep + weight conversion
    hipMemsetAsync(cnt_src, 0, 2 * 51200 * 4, stream);
    detect_kernel<<<1, 64, 0, stream>>>(dst, dflag);
    count_kernel<<<3125, 256, 0, stream>>>(src, dst, cnt_src, cnt_dst, dflag);
    scan_kernel<<<49, 1024, 0, stream>>>(cnt_dst, exc, bsums, N_NODES);
    scan_kernel<<<1, 1024, 0, stream>>>(bsums, bexc, bdummy, 49);
    finalize_kernel<<<196, 256, 0, stream>>>(exc, bexc, rp, cur,
                                             cnt_src, cnt_dst, norm_src, norm_dst);
    fill_kernel<<<3125, 256, 0, stream>>>(src, dst, cur, col, dflag);
    wconv_kernel<<<416, 256, 0, stream>>>(W1, W2, W3, W4, whi, wlo);

    const int GM = (N_NODES + 31) / 32;   // 1563 blocks
    const int SB = (N_NODES + 3) / 4;     // 12500 blocks (4 waves = 4 nodes)
    float* hid = out + (size_t)N_NODES * OUT_F;
    float* xcopy = hid + (size_t)N_NODES * H_F;

    // layer 1: 512 -> 128, relu  (fuses x passthrough copy into A-staging)
    gemm_mfma<128, true><<<GM, 256, 0, stream>>>(x, whi, wlo, norm_src, gbuf, IN_F, xcopy);
    spmm_kernel<128, true, true><<<SB, 256, 0, stream>>>(gbuf, rp, col, norm_dst, b1, hbuf, hid, emb, 1);

    // layer 2: 128 -> 128, relu
    gemm_mfma<128, false><<<GM, 256, 0, stream>>>(hbuf, whi + 65536, wlo + 65536, norm_src, gbuf, H_F, nullptr);
    spmm_kernel<128, true, true><<<SB, 256, 0, stream>>>(gbuf, rp, col, norm_dst, b2, hbuf, hid, emb, 2);

    // layer 3: 128 -> 128, relu
    gemm_mfma<128, false><<<GM, 256, 0, stream>>>(hbuf, whi + 81920, wlo + 81920, norm_src, gbuf, H_F, nullptr);
    spmm_kernel<128, true, true><<<SB, 256, 0, stream>>>(gbuf, rp, col, norm_dst, b3, hbuf, hid, emb, 3);

    // layer 4: 128 -> 64, no relu, straight into d_out
    gemm_mfma<64, false><<<GM, 256, 0, stream>>>(hbuf, whi + 98304, wlo + 98304, norm_src, gbuf, H_F, nullptr);
    spmm_kernel<64, false, false><<<SB, 256, 0, stream>>>(gbuf, rp, col, norm_dst, b4, out, nullptr, nullptr, 0);
}

// Round 10
// 618.530 us; speedup vs baseline: 1.2195x; 1.0486x over previous
//
#include <hip/hip_runtime.h>

#define N_NODES 50000
#define N_EDGES 800000
#define IN_F 512
#define H_F 128
#define OUT_F 64

// ---------------- graph prep ----------------
// Harness ABI says integer -> const int*, but reference declares int64.
// Auto-detect: read first 256 entries as int64; all in [0,N_NODES) => int64.

__global__ void detect_kernel(const void* __restrict__ edges, int* __restrict__ flag) {
    if (threadIdx.x == 0 && blockIdx.x == 0) {
        const long long* p = (const long long*)edges;
        int is64 = 1;
        for (int k = 0; k < 256; k++) {
            long long v = p[k];
            if (v < 0 || v >= N_NODES) { is64 = 0; break; }
        }
        flag[0] = is64;
    }
}

__device__ __forceinline__ int edge_at(const void* __restrict__ p, int e, int is64) {
    return is64 ? (int)((const long long*)p)[e] : ((const int*)p)[e];
}

__global__ void count_kernel(const void* __restrict__ src, const void* __restrict__ dst,
                             int* __restrict__ cs, int* __restrict__ cd,
                             const int* __restrict__ flag) {
    int is64 = flag[0];
    int e = blockIdx.x * 256 + threadIdx.x;
    if (e < N_EDGES) {
        atomicAdd(&cs[edge_at(src, e, is64)], 1);
        atomicAdd(&cd[edge_at(dst, e, is64)], 1);
    }
}

__global__ void scan_kernel(const int* __restrict__ in, int* __restrict__ exc,
                            int* __restrict__ bsums, int n) {
    __shared__ int tmp[1024];
    int tid = threadIdx.x;
    int gid = blockIdx.x * 1024 + tid;
    int v = (gid < n) ? in[gid] : 0;
    tmp[tid] = v;
    __syncthreads();
    for (int off = 1; off < 1024; off <<= 1) {
        int t = (tid >= off) ? tmp[tid - off] : 0;
        __syncthreads();
        tmp[tid] += t;
        __syncthreads();
    }
    if (gid < n) exc[gid] = tmp[tid] - v;   // exclusive
    if (tid == 1023) bsums[blockIdx.x] = tmp[1023];
}

__global__ void finalize_kernel(const int* __restrict__ exc, const int* __restrict__ bexc,
                                int* __restrict__ rp, int* __restrict__ cur,
                                const int* __restrict__ cs, const int* __restrict__ cd,
                                float* __restrict__ ns, float* __restrict__ nd) {
    int i = blockIdx.x * 256 + threadIdx.x;
    if (i < N_NODES) {
        int v = exc[i] + bexc[i >> 10];
        rp[i] = v;
        cur[i] = v;
        if (i == 0) rp[N_NODES] = N_EDGES;
        ns[i] = 1.0f / sqrtf(fmaxf((float)cs[i], 1.0f));
        nd[i] = 1.0f / sqrtf(fmaxf((float)cd[i], 1.0f));
    }
}

__global__ void fill_kernel(const void* __restrict__ src, const void* __restrict__ dst,
                            int* __restrict__ cur, int* __restrict__ col,
                            const int* __restrict__ flag) {
    int is64 = flag[0];
    int e = blockIdx.x * 256 + threadIdx.x;
    if (e < N_EDGES) {
        int d = edge_at(dst, e, is64);
        int pos = atomicAdd(&cur[d], 1);
        col[pos] = edge_at(src, e, is64);
    }
}

// ---------------- bf16 split helpers (RNE) ----------------

__device__ __forceinline__ ushort f2bf(float f) {
    unsigned int u = __float_as_uint(f);
    unsigned int r = u + 0x7FFFu + ((u >> 16) & 1u);
    return (ushort)(r >> 16);
}
__device__ __forceinline__ float bf2f(ushort h) {
    return __uint_as_float(((unsigned int)h) << 16);
}

// ---------------- W pre-convert: fp32 [K][N] -> fragment-linear bf16 hi/lo ----------------
// Frag element index for (k,n): kt=k>>5, kk=k&31, ns=n>>4;
// lane=(n&15)+16*(kk>>3), j=kk&7; dst = base + ((kt*NS+ns)*64+lane)*8 + j.
// k-map kappa(g,j)=8g+j is used identically for A and B staging, so the GEMM
// result is invariant to the hardware's internal k-ordering (consistent perm).

__global__ void wconv_kernel(const float* __restrict__ W1, const float* __restrict__ W2,
                             const float* __restrict__ W3, const float* __restrict__ W4,
                             ushort* __restrict__ hi, ushort* __restrict__ lo) {
    int id = blockIdx.x * 256 + threadIdx.x;
    const float* Wp; int N, rel, base;
    if (id < 65536)       { Wp = W1; N = 128; rel = id;          base = 0; }
    else if (id < 81920)  { Wp = W2; N = 128; rel = id - 65536;  base = 65536; }
    else if (id < 98304)  { Wp = W3; N = 128; rel = id - 81920;  base = 81920; }
    else if (id < 106496) { Wp = W4; N = 64;  rel = id - 98304;  base = 98304; }
    else return;
    int k = rel / N, n = rel % N;
    float v = Wp[rel];
    int NS = N >> 4;
    int kt = k >> 5, kk = k & 31, ns = n >> 4;
    int lane = (n & 15) + 16 * (kk >> 3), j = kk & 7;
    int dst = base + ((kt * NS + ns) * 64 + lane) * 8 + j;
    ushort h = f2bf(v);
    hi[dst] = h;
    lo[dst] = f2bf(v - bf2f(h));
}

// ---------------- GEMM via MFMA: C[M,N] = norm[row] * (A @ W), split-bf16 ----------------
// BM=64 rows/block (4 row-subtiles), 256 thr = 4 waves. Wave w owns ALL 4 rowsubs
// x NSW=N/64 n-subtiles (ns = w*NSW+q) -> each B fragment read ONCE per block
// (4x less L2 B-traffic than round-8's BM=32 layout) and 24 MFMAs per 4 B-pairs.
// Register double-buffer: aload(kt+1) issued before the LDS barrier (HBM latency
// spans MFMA phase), bload(kt+1) right after it (L2 latency spans MFMAs).
// 3 MFMAs per tile: hihi + hi*lo + lo*hi (lo*lo ~2^-16 dropped).
// C/D layout (HW-verified m89/m91): col=lane&15, row=(lane>>4)*4+reg.

typedef __attribute__((ext_vector_type(8))) short short8v;   // 8 bf16 (4 VGPRs)
typedef __attribute__((ext_vector_type(4))) float floatx4;

template <int N, bool COPY>
__global__ __launch_bounds__(256) void gemm_mfma(const float* __restrict__ A,
                                                 const ushort* __restrict__ Whi,
                                                 const ushort* __restrict__ Wlo,
                                                 const float* __restrict__ norm,
                                                 float* __restrict__ C, int K,
                                                 float* __restrict__ xc) {
    constexpr int NS = N / 16;       // 8 (N=128) / 4 (N=64)
    constexpr int NSW = NS / 4;      // n-subtiles per wave: 2 / 1

    __shared__ ushort Ahi[4][64][8];
    __shared__ ushort Alo[4][64][8];

    const int t = threadIdx.x;
    const int w = t >> 6, lane = t & 63;
    const int m0 = blockIdx.x * 64;
    const int KT = K >> 5;
    // staging coords: float4 p of thread t covers A[m0 + sr0 + 32p][kt*32 + sc .. +3]
    const int sr0 = t >> 3;                   // 0..31
    const int sc = (t & 7) << 2;              // 0,4,..,28

    floatx4 acc[4][NSW];
    #pragma unroll
    for (int rs = 0; rs < 4; rs++)
        #pragma unroll
        for (int q = 0; q < NSW; q++) acc[rs][q] = (floatx4)(0.0f);

    float4 a_cur0, a_cur1, a_nxt0, a_nxt1;
    short8v bh_cur[NSW], bl_cur[NSW], bh_nxt[NSW], bl_nxt[NSW];

    // prologue loads (kt=0)
    {
        int r0 = m0 + sr0, r1 = m0 + sr0 + 32;
        a_cur0 = make_float4(0.f, 0.f, 0.f, 0.f);
        a_cur1 = make_float4(0.f, 0.f, 0.f, 0.f);
        if (r0 < N_NODES) a_cur0 = *(const float4*)&A[(size_t)r0 * K + sc];
        if (r1 < N_NODES) a_cur1 = *(const float4*)&A[(size_t)r1 * K + sc];
        #pragma unroll
        for (int q = 0; q < NSW; q++) {
            size_t fb = ((size_t)(0 * NS + w * NSW + q) * 64 + lane) * 8;
            bh_cur[q] = *(const short8v*)&Whi[fb];
            bl_cur[q] = *(const short8v*)&Wlo[fb];
        }
    }

    for (int kt = 0; kt < KT; kt++) {
        if (kt > 0) __syncthreads();           // prior MFMA phase done reading LDS
        // split a_cur -> LDS (fragment-linear), fused xcopy on layer 1
        #pragma unroll
        for (int p = 0; p < 2; p++) {
            int r = sr0 + p * 32;
            float4 v = (p == 0) ? a_cur0 : a_cur1;
            if (COPY) {
                int row = m0 + r;
                if (row < N_NODES) *(float4*)&xc[(size_t)row * K + kt * 32 + sc] = v;
            }
            int ss = r >> 4;
            int sl = (r & 15) + 16 * (sc >> 3);
            int sj = sc & 7;
            ushort4 h4, l4;
            h4.x = f2bf(v.x); l4.x = f2bf(v.x - bf2f(h4.x));
            h4.y = f2bf(v.y); l4.y = f2bf(v.y - bf2f(h4.y));
            h4.z = f2bf(v.z); l4.z = f2bf(v.z - bf2f(h4.z));
            h4.w = f2bf(v.w); l4.w = f2bf(v.w - bf2f(h4.w));
            *(ushort4*)&Ahi[ss][sl][sj] = h4;
            *(ushort4*)&Alo[ss][sl][sj] = l4;
        }
        // prefetch A(kt+1): HBM latency spans the whole MFMA phase below
        if (kt + 1 < KT) {
            int r0 = m0 + sr0, r1 = m0 + sr0 + 32;
            a_nxt0 = make_float4(0.f, 0.f, 0.f, 0.f);
            a_nxt1 = make_float4(0.f, 0.f, 0.f, 0.f);
            if (r0 < N_NODES) a_nxt0 = *(const float4*)&A[(size_t)r0 * K + (kt + 1) * 32 + sc];
            if (r1 < N_NODES) a_nxt1 = *(const float4*)&A[(size_t)r1 * K + (kt + 1) * 32 + sc];
        }
        __syncthreads();
        // prefetch B(kt+1): L2 latency spans the MFMAs
        if (kt + 1 < KT) {
            #pragma unroll
            for (int q = 0; q < NSW; q++) {
                size_t fb = ((size_t)((kt + 1) * NS + w * NSW + q) * 64 + lane) * 8;
                bh_nxt[q] = *(const short8v*)&Whi[fb];
                bl_nxt[q] = *(const short8v*)&Wlo[fb];
            }
        }
        #pragma unroll
        for (int rs = 0; rs < 4; rs++) {
            short8v ah = *(const short8v*)&Ahi[rs][lane][0];
            short8v al = *(const short8v*)&Alo[rs][lane][0];
            #pragma unroll
            for (int q = 0; q < NSW; q++) {
                acc[rs][q] = __builtin_amdgcn_mfma_f32_16x16x32_bf16(ah, bh_cur[q], acc[rs][q], 0, 0, 0);
                acc[rs][q] = __builtin_amdgcn_mfma_f32_16x16x32_bf16(ah, bl_cur[q], acc[rs][q], 0, 0, 0);
                acc[rs][q] = __builtin_amdgcn_mfma_f32_16x16x32_bf16(al, bh_cur[q], acc[rs][q], 0, 0, 0);
            }
        }
        // rotate double-buffers (statically indexed)
        a_cur0 = a_nxt0; a_cur1 = a_nxt1;
        #pragma unroll
        for (int q = 0; q < NSW; q++) { bh_cur[q] = bh_nxt[q]; bl_cur[q] = bl_nxt[q]; }
    }

    // epilogue: C[gr][gc] = acc * norm[gr]
    #pragma unroll
    for (int rs = 0; rs < 4; rs++) {
        #pragma unroll
        for (int rr = 0; rr < 4; rr++) {
            int gr = m0 + rs * 16 + (lane >> 4) * 4 + rr;
            if (gr < N_NODES) {
                float s = norm[gr];
                #pragma unroll
                for (int q = 0; q < NSW; q++) {
                    int gc = (w * NSW + q) * 16 + (lane & 15);
                    C[(size_t)gr * N + gc] = acc[rs][q][rr] * s;
                }
            }
        }
    }
}

// ---------------- SpMM: out[i,:] = relu?(nd[i]*sum_{e in row i} h[col[e],:] + b) ----------
// One wave per node; lane holds float2 (FEAT=128) or float (FEAT=64).
// 8-edge unroll -> 8 gather loads in flight per wave. rp/col scalar via uniform i.

template <int FEAT, bool RELU, bool HID>
__global__ __launch_bounds__(256) void spmm_kernel(
        const float* __restrict__ h, const int* __restrict__ rp,
        const int* __restrict__ col, const float* __restrict__ nd,
        const float* __restrict__ bias, float* __restrict__ out,
        float* __restrict__ hid, const int* __restrict__ emb, int layer) {
    int i = blockIdx.x * 4 + (threadIdx.x >> 6);
    i = __builtin_amdgcn_readfirstlane(i);
    if (i >= N_NODES) return;
    int lane = threadIdx.x & 63;
    int beg = rp[i], end = rp[i + 1];

    if constexpr (FEAT == 128) {
        float ax = 0.f, ay = 0.f;
        int e = beg;
        for (; e + 8 <= end; e += 8) {
            int c0 = col[e], c1 = col[e+1], c2 = col[e+2], c3 = col[e+3];
            int c4 = col[e+4], c5 = col[e+5], c6 = col[e+6], c7 = col[e+7];
            float2 v0 = *(const float2*)&h[(size_t)c0 * FEAT + lane * 2];
            float2 v1 = *(const float2*)&h[(size_t)c1 * FEAT + lane * 2];
            float2 v2 = *(const float2*)&h[(size_t)c2 * FEAT + lane * 2];
            float2 v3 = *(const float2*)&h[(size_t)c3 * FEAT + lane * 2];
            float2 v4 = *(const float2*)&h[(size_t)c4 * FEAT + lane * 2];
            float2 v5 = *(const float2*)&h[(size_t)c5 * FEAT + lane * 2];
            float2 v6 = *(const float2*)&h[(size_t)c6 * FEAT + lane * 2];
            float2 v7 = *(const float2*)&h[(size_t)c7 * FEAT + lane * 2];
            ax += (v0.x + v1.x) + (v2.x + v3.x) + ((v4.x + v5.x) + (v6.x + v7.x));
            ay += (v0.y + v1.y) + (v2.y + v3.y) + ((v4.y + v5.y) + (v6.y + v7.y));
        }
        for (; e < end; e++) {
            float2 v = *(const float2*)&h[(size_t)col[e] * FEAT + lane * 2];
            ax += v.x; ay += v.y;
        }
        float s = nd[i];
        float2 b = *(const float2*)&bias[lane * 2];
        float vx = fmaf(ax, s, b.x), vy = fmaf(ay, s, b.y);
        if (RELU) { vx = fmaxf(vx, 0.f); vy = fmaxf(vy, 0.f); }
        float2 o = make_float2(vx, vy);
        *(float2*)&out[(size_t)i * FEAT + lane * 2] = o;
        if (HID) {
            if (emb[0] == layer) *(float2*)&hid[(size_t)i * FEAT + lane * 2] = o;
        }
    } else {
        float acc = 0.f;
        int e = beg;
        for (; e + 8 <= end; e += 8) {
            int c0 = col[e], c1 = col[e+1], c2 = col[e+2], c3 = col[e+3];
            int c4 = col[e+4], c5 = col[e+5], c6 = col[e+6], c7 = col[e+7];
            float v0 = h[(size_t)c0 * FEAT + lane];
            float v1 = h[(size_t)c1 * FEAT + lane];
            float v2 = h[(size_t)c2 * FEAT + lane];
            float v3 = h[(size_t)c3 * FEAT + lane];
            float v4 = h[(size_t)c4 * FEAT + lane];
            float v5 = h[(size_t)c5 * FEAT + lane];
            float v6 = h[(size_t)c6 * FEAT + lane];
            float v7 = h[(size_t)c7 * FEAT + lane];
            acc += (v0 + v1) + (v2 + v3) + ((v4 + v5) + (v6 + v7));
        }
        for (; e < end; e++) acc += h[(size_t)col[e] * FEAT + lane];
        float v = fmaf(acc, nd[i], bias[lane]);
        if (RELU) v = fmaxf(v, 0.f);
        out[(size_t)i * FEAT + lane] = v;
        if (HID) {
            if (emb[0] == layer) hid[(size_t)i * FEAT + lane] = v;
        }
    }
}

// ---------------- launch ----------------

extern "C" void kernel_launch(void* const* d_in, const int* in_sizes, int n_in,
                              void* d_out, int out_size, void* d_ws, size_t ws_size,
                              hipStream_t stream) {
    const float* x = (const float*)d_in[0];
    const void* src = d_in[1];
    const void* dst = d_in[2];
    const float* W1 = (const float*)d_in[3];  const float* b1 = (const float*)d_in[4];
    const float* W2 = (const float*)d_in[5];  const float* b2 = (const float*)d_in[6];
    const float* W3 = (const float*)d_in[7];  const float* b3 = (const float*)d_in[8];
    const float* W4 = (const float*)d_in[9];  const float* b4 = (const float*)d_in[10];
    const int* emb = (const int*)d_in[11];    // low word correct for int32 or int64
    float* out = (float*)d_out;

    // workspace carve-up (~54 MB)
    char* w = (char*)d_ws;
    int* cnt_src = (int*)w;  w += 51200 * 4;
    int* cnt_dst = (int*)w;  w += 51200 * 4;
    float* norm_src = (float*)w; w += 51200 * 4;
    float* norm_dst = (float*)w; w += 51200 * 4;
    int* exc = (int*)w;      w += 51200 * 4;
    int* bsums = (int*)w;    w += 1024 * 4;
    int* bexc = (int*)w;     w += 1024 * 4;
    int* bdummy = (int*)w;   w += 1024 * 4;
    int* dflag = (int*)w;    w += 1024 * 4;
    int* rp = (int*)w;       w += 51200 * 4;
    int* cur = (int*)w;      w += 51200 * 4;
    int* col = (int*)w;      w += 800768 * 4;
    float* gbuf = (float*)w; w += (size_t)6400000 * 4;   // GEMM output (pre-aggregation)
    float* hbuf = (float*)w; w += (size_t)6400000 * 4;   // SpMM output
    ushort* whi = (ushort*)w; w += 106496 * 2;           // W frags, bf16 hi
    ushort* wlo = (ushort*)w; w += 106496 * 2;           // W frags, bf16 lo

    // graph prep + weight conversion
    hipMemsetAsync(cnt_src, 0, 2 * 51200 * 4, stream);
    detect_kernel<<<1, 64, 0, stream>>>(dst, dflag);
    count_kernel<<<3125, 256, 0, stream>>>(src, dst, cnt_src, cnt_dst, dflag);
    scan_kernel<<<49, 1024, 0, stream>>>(cnt_dst, exc, bsums, N_NODES);
    scan_kernel<<<1, 1024, 0, stream>>>(bsums, bexc, bdummy, 49);
    finalize_kernel<<<196, 256, 0, stream>>>(exc, bexc, rp, cur,
                                             cnt_src, cnt_dst, norm_src, norm_dst);
    fill_kernel<<<3125, 256, 0, stream>>>(src, dst, cur, col, dflag);
    wconv_kernel<<<416, 256, 0, stream>>>(W1, W2, W3, W4, whi, wlo);

    const int GM = (N_NODES + 63) / 64;   // 782 blocks
    const int SB = (N_NODES + 3) / 4;     // 12500 blocks (4 waves = 4 nodes)
    float* hid = out + (size_t)N_NODES * OUT_F;
    float* xcopy = hid + (size_t)N_NODES * H_F;

    // layer 1: 512 -> 128, relu  (fuses x passthrough copy into A-staging)
    gemm_mfma<128, true><<<GM, 256, 0, stream>>>(x, whi, wlo, norm_src, gbuf, IN_F, xcopy);
    spmm_kernel<128, true, true><<<SB, 256, 0, stream>>>(gbuf, rp, col, norm_dst, b1, hbuf, hid, emb, 1);

    // layer 2: 128 -> 128, relu
    gemm_mfma<128, false><<<GM, 256, 0, stream>>>(hbuf, whi + 65536, wlo + 65536, norm_src, gbuf, H_F, nullptr);
    spmm_kernel<128, true, true><<<SB, 256, 0, stream>>>(gbuf, rp, col, norm_dst, b2, hbuf, hid, emb, 2);

    // layer 3: 128 -> 128, relu
    gemm_mfma<128, false><<<GM, 256, 0, stream>>>(hbuf, whi + 81920, wlo + 81920, norm_src, gbuf, H_F, nullptr);
    spmm_kernel<128, true, true><<<SB, 256, 0, stream>>>(gbuf, rp, col, norm_dst, b3, hbuf, hid, emb, 3);

    // layer 4: 128 -> 64, no relu, straight into d_out
    gemm_mfma<64, false><<<GM, 256, 0, stream>>>(hbuf, whi + 98304, wlo + 98304, norm_src, gbuf, H_F, nullptr);
    spmm_kernel<64, false, false><<<SB, 256, 0, stream>>>(gbuf, rp, col, norm_dst, b4, out, nullptr, nullptr, 0);
}